// Round 1
// baseline (331.359 us; speedup 1.0000x reference)
//
#include <hip/hip_runtime.h>

typedef __bf16 bf16;
typedef __bf16 bf16x8 __attribute__((ext_vector_type(8)));
typedef __bf16 bf16x4 __attribute__((ext_vector_type(4)));
typedef float  f32x4  __attribute__((ext_vector_type(4)));

#define T_TOTAL 9792
#define EMBED   1024
#define NHEAD   16
#define HDIM    64

// Fixed problem geometry (LENGTHS are compile-time constants of this problem).
__constant__ int c_seq_start[12] = {0,1024,1792,2688,3200,4224,4864,5888,6656,7168,8064,9088};
__constant__ int c_tiles_cum[13] = {0,16,28,42,50,66,76,92,104,112,126,142,153};

typedef __attribute__((address_space(1))) unsigned int gu32;
typedef __attribute__((address_space(3))) unsigned int lu32;

__device__ __forceinline__ void load_lds16(const void* g, void* l) {
    __builtin_amdgcn_global_load_lds((gu32*)g, (lu32*)l, 16, 0, 0);
}

__device__ __forceinline__ f32x4 mfma16(bf16x8 a, bf16x8 b, f32x4 c) {
    return __builtin_amdgcn_mfma_f32_16x16x32_bf16(a, b, c, 0, 0, 0);
}

// ---------------------------------------------------------------------------
// Fused dtype canonicalization: all 10 tensors in one dispatch.
// Discriminator: cos[0][0]==1.0 exactly -> fp32 first u16 is 0x0000.
// ---------------------------------------------------------------------------
struct CvtArgs {
    const void* src[10];
    bf16*       dst[10];
    int         n[10];
    int         cum[10];   // block offset of each segment
};

__global__ void to_bf16_fused(CvtArgs a, const unsigned short* __restrict__ disc)
{
    const bool f32 = (disc[0] == 0);
    const int blk = blockIdx.x;
    int seg = 0;
    #pragma unroll
    for (int i = 1; i < 10; ++i) if (blk >= a.cum[i]) seg = i;
    int i0 = (blk - a.cum[seg]) * 2048 + threadIdx.x * 8;
    if (i0 >= a.n[seg]) return;
    bf16x8 o;
    if (f32) {
        const float4* s = (const float4*)((const float*)a.src[seg] + i0);
        float4 x = s[0], y = s[1];
        o[0]=(bf16)x.x; o[1]=(bf16)x.y; o[2]=(bf16)x.z; o[3]=(bf16)x.w;
        o[4]=(bf16)y.x; o[5]=(bf16)y.y; o[6]=(bf16)y.z; o[7]=(bf16)y.w;
    } else {
        o = *(const bf16x8*)((const bf16*)a.src[seg] + i0);
    }
    *(bf16x8*)(a.dst[seg] + i0) = o;
}

// Supertile block map: 8 x-tiles per super-column x all NY, L2/L3 locality.
__device__ __forceinline__ void map_block2(int L, int NX, int NY, int& x, int& y)
{
    const int per = 8 * NY;
    const int nfull = NX >> 3;           // full supercols
    const int full = nfull * per;
    if (L < full) { int sc = L / per, rem = L % per; x = sc * 8 + (rem & 7); y = rem >> 3; }
    else {
        int rem = L - full;
        int tw = NX - nfull * 8;
        x = nfull * 8 + rem % tw; y = rem / tw;
    }
}

// ---------------------------------------------------------------------------
// 256x256 8-wave double-buffered GEMM core: acc = A[m0:+256] @ W[n0:+256]^T
// (K=1024, BK=64). Phase-split schedule:
//   iter kt: phase0 issues ALL 8 stage loads for kt+1 into buf p^1, then
//   4 quadrant-phases each {12 ds_read -> s_barrier -> lgkmcnt(0) ->
//   setprio(1) -> 16 MFMA -> setprio(0) -> s_barrier}; one vmcnt(0) per
//   K-tile at end of phase 3 (loads have ~4 phases of cover).
// XOR swizzle (granule ^ row&7) pre-applied on the GLOBAL side of staging;
// b128 fragment reads bank-conflict-free (verified pattern from R3).
// Safety: stage into a buffer is always after the barrier following the
// last completed read of it; reads of a fresh buffer always follow the
// per-wave vmcnt(0) + barrier. Uniform control flow for all barriers.
// ---------------------------------------------------------------------------
__device__ __forceinline__
void gemm_core256(const bf16* __restrict__ A, const bf16* __restrict__ W,
                  int M, int m0, int n0, f32x4 (&acc)[8][4],
                  bf16* lA, bf16* lB)
{
    const int tid  = threadIdx.x;
    const int wave = tid >> 6, lane = tid & 63;
    const int lrow = lane >> 3;
    const int gsw  = (lane & 7) ^ lrow;
    const int ln   = lane & 15, lq = lane >> 4;
    const int e7   = ln & 7;
    const int wm   = (wave >> 2) & 1;    // row half   [0,2)
    const int wn   = wave & 3;           // col quarter [0,4)

    auto stage = [&](int kt, int buf) {
        const int k0 = kt * 64;
        bf16* dA = lA + buf * (256 * 64);
        bf16* dB = lB + buf * (256 * 64);
        #pragma unroll
        for (int j = 0; j < 4; ++j) {
            int r = j * 64 + wave * 8;
            int gr = m0 + r + lrow; if (gr > M - 1) gr = M - 1;
            load_lds16(A + (size_t)gr * EMBED + k0 + gsw * 8, dA + r * 64);
            load_lds16(W + (size_t)(n0 + r + lrow) * EMBED + k0 + gsw * 8, dB + r * 64);
        }
    };

    stage(0, 0);
    __syncthreads();   // full drain once: buf0 staged before first reads

    for (int kt = 0; kt < 16; ++kt) {
        const int p = kt & 1;
        const bf16* sA = lA + p * (256 * 64);
        const bf16* sB = lB + p * (256 * 64);
        #pragma unroll
        for (int ph = 0; ph < 4; ++ph) {
            const int mh = ph >> 1, nh = ph & 1;
            if (ph == 0 && kt + 1 < 16) stage(kt + 1, p ^ 1);

            bf16x8 af[2][4], bfr[2][2];
            #pragma unroll
            for (int kb = 0; kb < 2; ++kb) {
                #pragma unroll
                for (int mi = 0; mi < 4; ++mi)
                    af[kb][mi] = *(const bf16x8*)
                        &sA[(wm * 128 + mh * 64 + mi * 16 + ln) * 64 + (((kb * 4 + lq) ^ e7) * 8)];
                #pragma unroll
                for (int niq = 0; niq < 2; ++niq)
                    bfr[kb][niq] = *(const bf16x8*)
                        &sB[(wn * 64 + nh * 32 + niq * 16 + ln) * 64 + (((kb * 4 + lq) ^ e7) * 8)];
            }
            __builtin_amdgcn_s_barrier();
            asm volatile("s_waitcnt lgkmcnt(0)" ::: "memory");
            __builtin_amdgcn_s_setprio(1);
            #pragma unroll
            for (int kb = 0; kb < 2; ++kb)
                #pragma unroll
                for (int mi = 0; mi < 4; ++mi)
                    #pragma unroll
                    for (int niq = 0; niq < 2; ++niq)
                        acc[mh * 4 + mi][nh * 2 + niq] =
                            mfma16(af[kb][mi], bfr[kb][niq], acc[mh * 4 + mi][nh * 2 + niq]);
            __builtin_amdgcn_s_setprio(0);
            if (ph == 3 && kt + 1 < 16)
                asm volatile("s_waitcnt vmcnt(0)" ::: "memory");
            __builtin_amdgcn_s_barrier();
        }
    }
}

// ---------------------------------------------------------------------------
// QKV fused GEMM. Grid 39*12. which = yy>>2 selects {Q,K,V}.
// Epilogue fuses: bias add, RoPE (Q,K; on fp32 acc), V transpose -> Vt.
// ---------------------------------------------------------------------------
__global__ __launch_bounds__(512, 2)
void gemm_qkv(const bf16* __restrict__ A,
              const bf16* __restrict__ Wq, const bf16* __restrict__ Wk,
              const bf16* __restrict__ Wv, const bf16* __restrict__ qb,
              const bf16* __restrict__ vb,
              const bf16* __restrict__ cosb, const bf16* __restrict__ sinb,
              bf16* __restrict__ Cq, bf16* __restrict__ Ck,
              bf16* __restrict__ Vt, int M)
{
    __shared__ __align__(16) bf16 lA[2 * 256 * 64];
    __shared__ __align__(16) bf16 lB[2 * 256 * 64];

    int x, yy;
    map_block2(blockIdx.x, 39, 12, x, yy);
    const int which = yy >> 2;
    const int m0 = x * 256, n0 = (yy & 3) * 256;   // n0 = col base within weight

    const bf16* W = (which == 0) ? Wq : (which == 1) ? Wk : Wv;
    f32x4 acc[8][4] = {};
    gemm_core256(A, W, M, m0, n0, acc, lA, lB);

    const int tid  = threadIdx.x;
    const int wave = tid >> 6, lane = tid & 63;
    const int ln   = lane & 15, lq = lane >> 4;
    const int wm   = (wave >> 2) & 1, wn = wave & 3;
    const int rbase = m0 + wm * 128;
    const int cbase = n0 + wn * 64;                // multiple of 64 (one head)

    if (which < 2) {
        // Q or K: bias (Q only) + RoPE on fp32 acc. Pair (d, d+32) = (ni, ni+2).
        bf16* C = (which == 0) ? Cq : Ck;
        const bf16* bias = (which == 0) ? qb : nullptr;
        #pragma unroll
        for (int mi = 0; mi < 8; ++mi) {
            int trow = rbase + mi * 16 + lq * 4;
            if (trow >= M) continue;
            #pragma unroll
            for (int ni = 0; ni < 2; ++ni) {
                int d    = ni * 16 + ln;           // in [0,32)
                int col0 = cbase + d;
                int col1 = col0 + 32;
                float b0 = bias ? (float)bias[col0] : 0.0f;
                float b1 = bias ? (float)bias[col1] : 0.0f;
                #pragma unroll
                for (int r = 0; r < 4; ++r) {
                    int t = trow + r;
                    float c = (float)cosb[t * HDIM + d];
                    float s = (float)sinb[t * HDIM + d];
                    float x0 = acc[mi][ni][r] + b0;
                    float x1 = acc[mi][ni + 2][r] + b1;
                    C[(size_t)t * EMBED + col0] = (bf16)(x0 * c - x1 * s);
                    C[(size_t)t * EMBED + col1] = (bf16)(x1 * c + x0 * s);
                }
            }
        }
    } else {
        // V: bias + direct transposed store Vt[(h*64+d) * T + t] (8B per (mi,ni))
        #pragma unroll
        for (int mi = 0; mi < 8; ++mi) {
            int trow = rbase + mi * 16 + lq * 4;
            if (trow >= M) continue;
            #pragma unroll
            for (int ni = 0; ni < 4; ++ni) {
                int d = ni * 16 + ln;
                float bv = (float)vb[cbase + d];
                bf16x4 o;
                #pragma unroll
                for (int r = 0; r < 4; ++r) o[r] = (bf16)(acc[mi][ni][r] + bv);
                *(bf16x4*)&Vt[(size_t)(cbase + d) * T_TOTAL + trow] = o;
            }
        }
    }
}

// ---------------------------------------------------------------------------
// Out-proj GEMM: writes d_out directly (fp32 or bf16 per disc). Grid 39*4.
// ---------------------------------------------------------------------------
__global__ __launch_bounds__(512, 2)
void gemm_out(const bf16* __restrict__ A, const bf16* __restrict__ W,
              const bf16* __restrict__ bias, void* __restrict__ out, int M,
              const unsigned short* __restrict__ disc)
{
    __shared__ __align__(16) bf16 lA[2 * 256 * 64];
    __shared__ __align__(16) bf16 lB[2 * 256 * 64];

    int x, yy;
    map_block2(blockIdx.x, 39, 4, x, yy);
    const int m0 = x * 256, n0 = yy * 256;

    f32x4 acc[8][4] = {};
    gemm_core256(A, W, M, m0, n0, acc, lA, lB);

    const bool f32 = (disc[0] == 0);
    const int tid  = threadIdx.x;
    const int wave = tid >> 6, lane = tid & 63;
    const int ln   = lane & 15, lq = lane >> 4;
    const int wm   = (wave >> 2) & 1, wn = wave & 3;
    const int rbase = m0 + wm * 128;
    const int cbase = n0 + wn * 64;

    #pragma unroll
    for (int mi = 0; mi < 8; ++mi) {
        int trow = rbase + mi * 16 + lq * 4;
        if (trow >= M) continue;
        #pragma unroll
        for (int ni = 0; ni < 4; ++ni) {
            int col = cbase + ni * 16 + ln;
            float bv = (float)bias[col];
            #pragma unroll
            for (int r = 0; r < 4; ++r) {
                float v = acc[mi][ni][r] + bv;
                size_t idx = (size_t)(trow + r) * EMBED + col;
                if (f32) ((float*)out)[idx] = v;
                else     ((bf16*)out)[idx]  = (bf16)v;
            }
        }
    }
}

// ---------------------------------------------------------------------------
// Flash attention, S^T formulation (unchanged — verified).
// ---------------------------------------------------------------------------
__global__ __launch_bounds__(256, 3)
void attn_kernel(const bf16* __restrict__ Q, const bf16* __restrict__ K,
                 const bf16* __restrict__ Vt, bf16* __restrict__ O)
{
    __shared__ __align__(16) bf16 sK[2][64 * 64];
    __shared__ __align__(16) bf16 sV[2][64 * 64];       // Vt tile: [dh][kv]
    __shared__ __align__(16) bf16 sQP[4 * 16 * 72];     // Q tile, later per-wave P

    const int tid  = threadIdx.x;
    const int wave = tid >> 6, lane = tid & 63;
    const int lrow = lane >> 3;
    const int gsw  = (lane & 7) ^ lrow;
    const int ln   = lane & 15, lq = lane >> 4;
    const int e7   = ln & 7;
    const int h = blockIdx.y;

    int b = 0;
    #pragma unroll
    for (int i = 1; i < 13; ++i) if ((int)blockIdx.x >= c_tiles_cum[i]) b = i;
    const int qt = blockIdx.x - c_tiles_cum[b];
    const int t0 = c_seq_start[b] + qt * 64;
    const int kvb0 = c_seq_start[b];

    for (int p = 0; p < 2; ++p) {
        int r = p * 32 + wave * 8;
        load_lds16(Q  + (size_t)(t0 + r + lrow) * EMBED + h * HDIM + gsw * 8, &sQP[r * 64]);
        load_lds16(K  + (size_t)(kvb0 + r + lrow) * EMBED + h * HDIM + gsw * 8, &sK[0][r * 64]);
        load_lds16(Vt + (size_t)(h * HDIM + r + lrow) * T_TOTAL + kvb0 + gsw * 8, &sV[0][r * 64]);
    }

    bf16x8 qf[2];
    f32x4 oacc[4] = {};
    float m_i = -1e30f, l_i = 0.0f;
    const float sc = 0.125f * 1.44269504088896f;
    const int q_loc = wave * 16 + ln;
    bf16* sP = &sQP[wave * 16 * 72];

    for (int j = 0; j <= qt; ++j) {
        __syncthreads();
        const int cur = j & 1;
        if (j == 0) {
            qf[0] = *(const bf16x8*)&sQP[q_loc * 64 + ((0 + lq) ^ e7) * 8];
            qf[1] = *(const bf16x8*)&sQP[q_loc * 64 + ((4 + lq) ^ e7) * 8];
            __syncthreads();
        }
        if (j < qt) {
            const int kvb = kvb0 + (j + 1) * 64;
            const int nxt = cur ^ 1;
            for (int p = 0; p < 2; ++p) {
                int r = p * 32 + wave * 8;
                load_lds16(K  + (size_t)(kvb + r + lrow) * EMBED + h * HDIM + gsw * 8, &sK[nxt][r * 64]);
                load_lds16(Vt + (size_t)(h * HDIM + r + lrow) * T_TOTAL + kvb + gsw * 8, &sV[nxt][r * 64]);
            }
        }

        f32x4 s[4] = {};
        #pragma unroll
        for (int kk = 0; kk < 2; ++kk)
            #pragma unroll
            for (int ni = 0; ni < 4; ++ni) {
                bf16x8 kf = *(const bf16x8*)&sK[cur][(ni * 16 + ln) * 64 + (((kk * 4 + lq) ^ e7) * 8)];
                s[ni] = mfma16(kf, qf[kk], s[ni]);      // S^T[kv][q]
            }

        float pb[4][4];
        if (j == qt) {
            #pragma unroll
            for (int ni = 0; ni < 4; ++ni)
                #pragma unroll
                for (int r = 0; r < 4; ++r) {
                    int kv = ni * 16 + lq * 4 + r;
                    pb[ni][r] = (kv <= q_loc) ? s[ni][r] * sc : -1e30f;
                }
        } else {
            #pragma unroll
            for (int ni = 0; ni < 4; ++ni)
                #pragma unroll
                for (int r = 0; r < 4; ++r)
                    pb[ni][r] = s[ni][r] * sc;
        }

        float mx = pb[0][0];
        #pragma unroll
        for (int ni = 0; ni < 4; ++ni)
            #pragma unroll
            for (int r = 0; r < 4; ++r) mx = fmaxf(mx, pb[ni][r]);
        mx = fmaxf(mx, __shfl_xor(mx, 16));
        mx = fmaxf(mx, __shfl_xor(mx, 32));
        float mnew  = fmaxf(m_i, mx);
        float alpha = exp2f(m_i - mnew);
        m_i = mnew;

        float rs = 0.0f;
        #pragma unroll
        for (int ni = 0; ni < 4; ++ni)
            #pragma unroll
            for (int r = 0; r < 4; ++r) {
                float pe = exp2f(pb[ni][r] - mnew);
                pb[ni][r] = pe;
                rs += pe;
            }
        rs += __shfl_xor(rs, 16);
        rs += __shfl_xor(rs, 32);
        l_i = l_i * alpha + rs;
        #pragma unroll
        for (int d = 0; d < 4; ++d)
            #pragma unroll
            for (int r = 0; r < 4; ++r) oacc[d][r] *= alpha;

        #pragma unroll
        for (int ni = 0; ni < 4; ++ni) {
            bf16x4 w4;
            #pragma unroll
            for (int r = 0; r < 4; ++r) w4[r] = (bf16)pb[ni][r];
            *(bf16x4*)&sP[ln * 72 + ni * 16 + lq * 4] = w4;
        }
        asm volatile("s_waitcnt lgkmcnt(0)" ::: "memory");

        #pragma unroll
        for (int kk = 0; kk < 2; ++kk) {
            bf16x8 pf = *(const bf16x8*)&sP[ln * 72 + kk * 32 + lq * 8];
            #pragma unroll
            for (int d = 0; d < 4; ++d) {
                bf16x8 vf = *(const bf16x8*)&sV[cur][(d * 16 + ln) * 64 + (((kk * 4 + lq) ^ e7) * 8)];
                oacc[d] = mfma16(vf, pf, oacc[d]);      // O^T[dh][q]
            }
        }
    }

    const float inv = 1.0f / l_i;
    const size_t row = (size_t)(t0 + q_loc) * EMBED + h * HDIM;
    #pragma unroll
    for (int d = 0; d < 4; ++d) {
        bf16x4 o4;
        #pragma unroll
        for (int r = 0; r < 4; ++r) o4[r] = (bf16)(oacc[d][r] * inv);
        *(bf16x4*)&O[row + d * 16 + lq * 4] = o4;
    }
}

// ---------------------------------------------------------------------------
extern "C" void kernel_launch(void* const* d_in, const int* in_sizes, int n_in,
                              void* d_out, int out_size, void* d_ws, size_t ws_size,
                              hipStream_t stream)
{
    const unsigned short* disc = (const unsigned short*)d_in[1];  // cos[0][0]

    const size_t SZ  = (size_t)T_TOTAL * EMBED;   // 10,027,008
    const size_t CS  = (size_t)T_TOTAL * HDIM;    // 626,688
    const size_t WSZ = (size_t)EMBED * EMBED;     // 1,048,576

    bf16* p = (bf16*)d_ws;
    bf16* ch   = p; p += SZ;
    bf16* ccos = p; p += CS;
    bf16* csin = p; p += CS;
    bf16* cqw  = p; p += WSZ;
    bf16* ckw  = p; p += WSZ;
    bf16* cvw  = p; p += WSZ;
    bf16* cow  = p; p += WSZ;
    bf16* cqb  = p; p += EMBED;
    bf16* cvb  = p; p += EMBED;
    bf16* cob  = p; p += EMBED;
    bf16* wq   = p; p += SZ;      // Q (post-RoPE), then attention output (in place)
    bf16* wk   = p; p += SZ;
    bf16* wvt  = p; p += SZ;      // V^T per head

    CvtArgs ca;
    const void* srcs[10] = {d_in[0], d_in[1], d_in[2], d_in[3], d_in[5],
                            d_in[6], d_in[8], d_in[4], d_in[7], d_in[9]};
    bf16* dsts[10] = {ch, ccos, csin, cqw, ckw, cvw, cow, cqb, cvb, cob};
    int   ns[10]   = {(int)SZ, (int)CS, (int)CS, (int)WSZ, (int)WSZ,
                      (int)WSZ, (int)WSZ, EMBED, EMBED, EMBED};
    int cum = 0;
    for (int i = 0; i < 10; ++i) {
        ca.src[i] = srcs[i]; ca.dst[i] = dsts[i]; ca.n[i] = ns[i];
        ca.cum[i] = cum;
        cum += (ns[i] + 2047) / 2048;
    }
    to_bf16_fused<<<cum, 256, 0, stream>>>(ca, disc);

    gemm_qkv<<<39 * 12, 512, 0, stream>>>(ch, cqw, ckw, cvw, cqb, cvb,
                                          ccos, csin, wq, wk, wvt, T_TOTAL);
    attn_kernel<<<dim3(153, 16), 256, 0, stream>>>(wq, wk, wvt, wq);
    gemm_out<<<39 * 4, 512, 0, stream>>>(wq, cow, cob, d_out, T_TOTAL, disc);
}

// Round 2
// 303.476 us; speedup vs baseline: 1.0919x; 1.0919x over previous
//
#include <hip/hip_runtime.h>

typedef __bf16 bf16;
typedef __bf16 bf16x8 __attribute__((ext_vector_type(8)));
typedef __bf16 bf16x4 __attribute__((ext_vector_type(4)));
typedef float  f32x4  __attribute__((ext_vector_type(4)));

#define T_TOTAL 9792
#define EMBED   1024
#define NHEAD   16
#define HDIM    64

// Fixed problem geometry (LENGTHS are compile-time constants of this problem).
__constant__ int c_seq_start[12] = {0,1024,1792,2688,3200,4224,4864,5888,6656,7168,8064,9088};
__constant__ int c_tiles_cum[13] = {0,16,28,42,50,66,76,92,104,112,126,142,153};

typedef __attribute__((address_space(1))) unsigned int gu32;
typedef __attribute__((address_space(3))) unsigned int lu32;

__device__ __forceinline__ void load_lds16(const void* g, void* l) {
    __builtin_amdgcn_global_load_lds((gu32*)g, (lu32*)l, 16, 0, 0);
}

__device__ __forceinline__ f32x4 mfma16(bf16x8 a, bf16x8 b, f32x4 c) {
    return __builtin_amdgcn_mfma_f32_16x16x32_bf16(a, b, c, 0, 0, 0);
}

// ---------------------------------------------------------------------------
// Fused dtype canonicalization: all 10 tensors in one dispatch.
// Discriminator: cos[0][0]==1.0 exactly -> fp32 first u16 is 0x0000.
// ---------------------------------------------------------------------------
struct CvtArgs {
    const void* src[10];
    bf16*       dst[10];
    int         n[10];
    int         cum[10];   // block offset of each segment
};

__global__ void to_bf16_fused(CvtArgs a, const unsigned short* __restrict__ disc)
{
    const bool f32 = (disc[0] == 0);
    const int blk = blockIdx.x;
    int seg = 0;
    #pragma unroll
    for (int i = 1; i < 10; ++i) if (blk >= a.cum[i]) seg = i;
    int i0 = (blk - a.cum[seg]) * 2048 + threadIdx.x * 8;
    if (i0 >= a.n[seg]) return;
    bf16x8 o;
    if (f32) {
        const float4* s = (const float4*)((const float*)a.src[seg] + i0);
        float4 x = s[0], y = s[1];
        o[0]=(bf16)x.x; o[1]=(bf16)x.y; o[2]=(bf16)x.z; o[3]=(bf16)x.w;
        o[4]=(bf16)y.x; o[5]=(bf16)y.y; o[6]=(bf16)y.z; o[7]=(bf16)y.w;
    } else {
        o = *(const bf16x8*)((const bf16*)a.src[seg] + i0);
    }
    *(bf16x8*)(a.dst[seg] + i0) = o;
}

// Supertile block map: 8 x-tiles per super-column x all NY, L2/L3 locality.
__device__ __forceinline__ void map_block2(int L, int NX, int NY, int& x, int& y)
{
    const int per = 8 * NY;
    const int nfull = NX >> 3;           // full supercols
    const int full = nfull * per;
    if (L < full) { int sc = L / per, rem = L % per; x = sc * 8 + (rem & 7); y = rem >> 3; }
    else {
        int rem = L - full;
        int tw = NX - nfull * 8;
        x = nfull * 8 + rem % tw; y = rem / tw;
    }
}

// ---------------------------------------------------------------------------
// 256x256 8-wave GEMM core, BK=32, 4-buffer / 3-deep counted-vmcnt pipeline:
//   body(t): vmcnt(8) [oldest tile landed; 2 tiles stay in flight] ->
//   s_barrier -> stage(t+3) into buf (t-1)&3 -> 12 ds_read_b128 (tile t) ->
//   setprio(1) 32 MFMA setprio(0).  NEVER drains vmcnt to 0 in steady state.
// Hazards: RAW: vmcnt+barrier precede reads of tile t (all waves' loads
//   visible). WAR: stage(t+3) writes buf (t-1)&3; every wave's tile-(t-1)
//   ds_reads completed (its own lgkm wait) before it arrives at this
//   barrier, so the overwrite is ordered after all reads.
// Bank conflicts: BK=32 -> 64B row stride; a fragment read's lanes 0..7
//   cover banks 0..31 exactly (rows {0,1} x 4 granules) -> linear layout is
//   conflict-free; no swizzle anywhere. Stage writes are lane-contiguous.
// ---------------------------------------------------------------------------
__device__ __forceinline__
void gemm_core256(const bf16* __restrict__ A, const bf16* __restrict__ W,
                  int M, int m0, int n0, f32x4 (&acc)[8][4], bf16* lds)
{
    const int tid  = threadIdx.x;
    const int wave = tid >> 6, lane = tid & 63;
    const int ln   = lane & 15, lq = lane >> 4;
    const int wm   = (wave >> 2) & 1;    // row half    [0,2)
    const int wn   = wave & 3;           // col quarter [0,4)

    // stage thread mapping: 512 threads x 16B = 8KB = 128 rows x 64B
    const int srow = tid >> 2;           // row within 128-row group
    const int sg   = (tid & 3) * 8;      // element offset in 32-elem row

    int r0 = m0 + srow;        if (r0 > M - 1) r0 = M - 1;
    int r1 = m0 + 128 + srow;  if (r1 > M - 1) r1 = M - 1;
    const bf16* gA0 = A + (size_t)r0 * EMBED + sg;
    const bf16* gA1 = A + (size_t)r1 * EMBED + sg;
    const bf16* gB0 = W + (size_t)(n0 + srow) * EMBED + sg;
    const bf16* gB1 = W + (size_t)(n0 + 128 + srow) * EMBED + sg;

    auto stage = [&](int t) {
        const int k0 = t * 32;
        bf16* dA = lds + (t & 3) * 16384;      // 8192 A + 8192 B elems per buf
        bf16* dB = dA + 8192;
        load_lds16(gA0 + k0, dA + tid * 8);
        load_lds16(gA1 + k0, dA + 4096 + tid * 8);
        load_lds16(gB0 + k0, dB + tid * 8);
        load_lds16(gB1 + k0, dB + 4096 + tid * 8);
    };

    stage(0); stage(1); stage(2);

    const int aoff = (wm * 128 + ln) * 32 + lq * 8;
    const int boff = (wn * 64  + ln) * 32 + lq * 8;

    for (int t = 0; t < 32; ++t) {
        if (t < 30)       asm volatile("s_waitcnt vmcnt(8)" ::: "memory");
        else if (t == 30) asm volatile("s_waitcnt vmcnt(4)" ::: "memory");
        else              asm volatile("s_waitcnt vmcnt(0)" ::: "memory");
        __builtin_amdgcn_s_barrier();
        if (t + 3 < 32) stage(t + 3);

        const bf16* sA = lds + (t & 3) * 16384;
        const bf16* sB = sA + 8192;
        bf16x8 af[8], bfr[4];
        #pragma unroll
        for (int mi = 0; mi < 8; ++mi)
            af[mi] = *(const bf16x8*)&sA[aoff + mi * 512];
        #pragma unroll
        for (int ni = 0; ni < 4; ++ni)
            bfr[ni] = *(const bf16x8*)&sB[boff + ni * 512];

        __builtin_amdgcn_s_setprio(1);
        #pragma unroll
        for (int mi = 0; mi < 8; ++mi)
            #pragma unroll
            for (int ni = 0; ni < 4; ++ni)
                acc[mi][ni] = mfma16(af[mi], bfr[ni], acc[mi][ni]);
        __builtin_amdgcn_s_setprio(0);
    }
}

// ---------------------------------------------------------------------------
// QKV fused GEMM. Grid 39*12. which = yy>>2 selects {Q,K,V}.
// Epilogue fuses: bias add, RoPE (Q,K; on fp32 acc), V transpose -> Vt.
// ---------------------------------------------------------------------------
__global__ __launch_bounds__(512, 2)
void gemm_qkv(const bf16* __restrict__ A,
              const bf16* __restrict__ Wq, const bf16* __restrict__ Wk,
              const bf16* __restrict__ Wv, const bf16* __restrict__ qb,
              const bf16* __restrict__ vb,
              const bf16* __restrict__ cosb, const bf16* __restrict__ sinb,
              bf16* __restrict__ Cq, bf16* __restrict__ Ck,
              bf16* __restrict__ Vt, int M)
{
    __shared__ __align__(16) bf16 lds[4 * 16384];

    int x, yy;
    map_block2(blockIdx.x, 39, 12, x, yy);
    const int which = yy >> 2;
    const int m0 = x * 256, n0 = (yy & 3) * 256;   // n0 = col base within weight

    const bf16* W = (which == 0) ? Wq : (which == 1) ? Wk : Wv;
    f32x4 acc[8][4] = {};
    gemm_core256(A, W, M, m0, n0, acc, lds);

    const int tid  = threadIdx.x;
    const int wave = tid >> 6, lane = tid & 63;
    const int ln   = lane & 15, lq = lane >> 4;
    const int wm   = (wave >> 2) & 1, wn = wave & 3;
    const int rbase = m0 + wm * 128;
    const int cbase = n0 + wn * 64;                // multiple of 64 (one head)

    if (which < 2) {
        // Q or K: bias (Q only) + RoPE on fp32 acc. Pair (d, d+32) = (ni, ni+2).
        bf16* C = (which == 0) ? Cq : Ck;
        const bf16* bias = (which == 0) ? qb : nullptr;
        #pragma unroll
        for (int mi = 0; mi < 8; ++mi) {
            int trow = rbase + mi * 16 + lq * 4;
            if (trow >= M) continue;
            #pragma unroll
            for (int ni = 0; ni < 2; ++ni) {
                int d    = ni * 16 + ln;           // in [0,32)
                int col0 = cbase + d;
                int col1 = col0 + 32;
                float b0 = bias ? (float)bias[col0] : 0.0f;
                float b1 = bias ? (float)bias[col1] : 0.0f;
                #pragma unroll
                for (int r = 0; r < 4; ++r) {
                    int t = trow + r;
                    float c = (float)cosb[t * HDIM + d];
                    float s = (float)sinb[t * HDIM + d];
                    float x0 = acc[mi][ni][r] + b0;
                    float x1 = acc[mi][ni + 2][r] + b1;
                    C[(size_t)t * EMBED + col0] = (bf16)(x0 * c - x1 * s);
                    C[(size_t)t * EMBED + col1] = (bf16)(x1 * c + x0 * s);
                }
            }
        }
    } else {
        // V: bias + direct transposed store Vt[(h*64+d) * T + t] (8B per (mi,ni))
        #pragma unroll
        for (int mi = 0; mi < 8; ++mi) {
            int trow = rbase + mi * 16 + lq * 4;
            if (trow >= M) continue;
            #pragma unroll
            for (int ni = 0; ni < 4; ++ni) {
                int d = ni * 16 + ln;
                float bv = (float)vb[cbase + d];
                bf16x4 o;
                #pragma unroll
                for (int r = 0; r < 4; ++r) o[r] = (bf16)(acc[mi][ni][r] + bv);
                *(bf16x4*)&Vt[(size_t)(cbase + d) * T_TOTAL + trow] = o;
            }
        }
    }
}

// ---------------------------------------------------------------------------
// Out-proj GEMM: writes d_out directly (fp32 or bf16 per disc). Grid 39*4.
// ---------------------------------------------------------------------------
__global__ __launch_bounds__(512, 2)
void gemm_out(const bf16* __restrict__ A, const bf16* __restrict__ W,
              const bf16* __restrict__ bias, void* __restrict__ out, int M,
              const unsigned short* __restrict__ disc)
{
    __shared__ __align__(16) bf16 lds[4 * 16384];

    int x, yy;
    map_block2(blockIdx.x, 39, 4, x, yy);
    const int m0 = x * 256, n0 = yy * 256;

    f32x4 acc[8][4] = {};
    gemm_core256(A, W, M, m0, n0, acc, lds);

    const bool f32 = (disc[0] == 0);
    const int tid  = threadIdx.x;
    const int wave = tid >> 6, lane = tid & 63;
    const int ln   = lane & 15, lq = lane >> 4;
    const int wm   = (wave >> 2) & 1, wn = wave & 3;
    const int rbase = m0 + wm * 128;
    const int cbase = n0 + wn * 64;

    #pragma unroll
    for (int mi = 0; mi < 8; ++mi) {
        int trow = rbase + mi * 16 + lq * 4;
        if (trow >= M) continue;
        #pragma unroll
        for (int ni = 0; ni < 4; ++ni) {
            int col = cbase + ni * 16 + ln;
            float bv = (float)bias[col];
            #pragma unroll
            for (int r = 0; r < 4; ++r) {
                float v = acc[mi][ni][r] + bv;
                size_t idx = (size_t)(trow + r) * EMBED + col;
                if (f32) ((float*)out)[idx] = v;
                else     ((bf16*)out)[idx]  = (bf16)v;
            }
        }
    }
}

// ---------------------------------------------------------------------------
// Flash attention, S^T formulation (unchanged — verified).
// ---------------------------------------------------------------------------
__global__ __launch_bounds__(256, 3)
void attn_kernel(const bf16* __restrict__ Q, const bf16* __restrict__ K,
                 const bf16* __restrict__ Vt, bf16* __restrict__ O)
{
    __shared__ __align__(16) bf16 sK[2][64 * 64];
    __shared__ __align__(16) bf16 sV[2][64 * 64];       // Vt tile: [dh][kv]
    __shared__ __align__(16) bf16 sQP[4 * 16 * 72];     // Q tile, later per-wave P

    const int tid  = threadIdx.x;
    const int wave = tid >> 6, lane = tid & 63;
    const int lrow = lane >> 3;
    const int gsw  = (lane & 7) ^ lrow;
    const int ln   = lane & 15, lq = lane >> 4;
    const int e7   = ln & 7;
    const int h = blockIdx.y;

    int b = 0;
    #pragma unroll
    for (int i = 1; i < 13; ++i) if ((int)blockIdx.x >= c_tiles_cum[i]) b = i;
    const int qt = blockIdx.x - c_tiles_cum[b];
    const int t0 = c_seq_start[b] + qt * 64;
    const int kvb0 = c_seq_start[b];

    for (int p = 0; p < 2; ++p) {
        int r = p * 32 + wave * 8;
        load_lds16(Q  + (size_t)(t0 + r + lrow) * EMBED + h * HDIM + gsw * 8, &sQP[r * 64]);
        load_lds16(K  + (size_t)(kvb0 + r + lrow) * EMBED + h * HDIM + gsw * 8, &sK[0][r * 64]);
        load_lds16(Vt + (size_t)(h * HDIM + r + lrow) * T_TOTAL + kvb0 + gsw * 8, &sV[0][r * 64]);
    }

    bf16x8 qf[2];
    f32x4 oacc[4] = {};
    float m_i = -1e30f, l_i = 0.0f;
    const float sc = 0.125f * 1.44269504088896f;
    const int q_loc = wave * 16 + ln;
    bf16* sP = &sQP[wave * 16 * 72];

    for (int j = 0; j <= qt; ++j) {
        __syncthreads();
        const int cur = j & 1;
        if (j == 0) {
            qf[0] = *(const bf16x8*)&sQP[q_loc * 64 + ((0 + lq) ^ e7) * 8];
            qf[1] = *(const bf16x8*)&sQP[q_loc * 64 + ((4 + lq) ^ e7) * 8];
            __syncthreads();
        }
        if (j < qt) {
            const int kvb = kvb0 + (j + 1) * 64;
            const int nxt = cur ^ 1;
            for (int p = 0; p < 2; ++p) {
                int r = p * 32 + wave * 8;
                load_lds16(K  + (size_t)(kvb + r + lrow) * EMBED + h * HDIM + gsw * 8, &sK[nxt][r * 64]);
                load_lds16(Vt + (size_t)(h * HDIM + r + lrow) * T_TOTAL + kvb + gsw * 8, &sV[nxt][r * 64]);
            }
        }

        f32x4 s[4] = {};
        #pragma unroll
        for (int kk = 0; kk < 2; ++kk)
            #pragma unroll
            for (int ni = 0; ni < 4; ++ni) {
                bf16x8 kf = *(const bf16x8*)&sK[cur][(ni * 16 + ln) * 64 + (((kk * 4 + lq) ^ e7) * 8)];
                s[ni] = mfma16(kf, qf[kk], s[ni]);      // S^T[kv][q]
            }

        float pb[4][4];
        if (j == qt) {
            #pragma unroll
            for (int ni = 0; ni < 4; ++ni)
                #pragma unroll
                for (int r = 0; r < 4; ++r) {
                    int kv = ni * 16 + lq * 4 + r;
                    pb[ni][r] = (kv <= q_loc) ? s[ni][r] * sc : -1e30f;
                }
        } else {
            #pragma unroll
            for (int ni = 0; ni < 4; ++ni)
                #pragma unroll
                for (int r = 0; r < 4; ++r)
                    pb[ni][r] = s[ni][r] * sc;
        }

        float mx = pb[0][0];
        #pragma unroll
        for (int ni = 0; ni < 4; ++ni)
            #pragma unroll
            for (int r = 0; r < 4; ++r) mx = fmaxf(mx, pb[ni][r]);
        mx = fmaxf(mx, __shfl_xor(mx, 16));
        mx = fmaxf(mx, __shfl_xor(mx, 32));
        float mnew  = fmaxf(m_i, mx);
        float alpha = exp2f(m_i - mnew);
        m_i = mnew;

        float rs = 0.0f;
        #pragma unroll
        for (int ni = 0; ni < 4; ++ni)
            #pragma unroll
            for (int r = 0; r < 4; ++r) {
                float pe = exp2f(pb[ni][r] - mnew);
                pb[ni][r] = pe;
                rs += pe;
            }
        rs += __shfl_xor(rs, 16);
        rs += __shfl_xor(rs, 32);
        l_i = l_i * alpha + rs;
        #pragma unroll
        for (int d = 0; d < 4; ++d)
            #pragma unroll
            for (int r = 0; r < 4; ++r) oacc[d][r] *= alpha;

        #pragma unroll
        for (int ni = 0; ni < 4; ++ni) {
            bf16x4 w4;
            #pragma unroll
            for (int r = 0; r < 4; ++r) w4[r] = (bf16)pb[ni][r];
            *(bf16x4*)&sP[ln * 72 + ni * 16 + lq * 4] = w4;
        }
        asm volatile("s_waitcnt lgkmcnt(0)" ::: "memory");

        #pragma unroll
        for (int kk = 0; kk < 2; ++kk) {
            bf16x8 pf = *(const bf16x8*)&sP[ln * 72 + kk * 32 + lq * 8];
            #pragma unroll
            for (int d = 0; d < 4; ++d) {
                bf16x8 vf = *(const bf16x8*)&sV[cur][(d * 16 + ln) * 64 + (((kk * 4 + lq) ^ e7) * 8)];
                oacc[d] = mfma16(vf, pf, oacc[d]);      // O^T[dh][q]
            }
        }
    }

    const float inv = 1.0f / l_i;
    const size_t row = (size_t)(t0 + q_loc) * EMBED + h * HDIM;
    #pragma unroll
    for (int d = 0; d < 4; ++d) {
        bf16x4 o4;
        #pragma unroll
        for (int r = 0; r < 4; ++r) o4[r] = (bf16)(oacc[d][r] * inv);
        *(bf16x4*)&O[row + d * 16 + lq * 4] = o4;
    }
}

// ---------------------------------------------------------------------------
extern "C" void kernel_launch(void* const* d_in, const int* in_sizes, int n_in,
                              void* d_out, int out_size, void* d_ws, size_t ws_size,
                              hipStream_t stream)
{
    const unsigned short* disc = (const unsigned short*)d_in[1];  // cos[0][0]

    const size_t SZ  = (size_t)T_TOTAL * EMBED;   // 10,027,008
    const size_t CS  = (size_t)T_TOTAL * HDIM;    // 626,688
    const size_t WSZ = (size_t)EMBED * EMBED;     // 1,048,576

    bf16* p = (bf16*)d_ws;
    bf16* ch   = p; p += SZ;
    bf16* ccos = p; p += CS;
    bf16* csin = p; p += CS;
    bf16* cqw  = p; p += WSZ;
    bf16* ckw  = p; p += WSZ;
    bf16* cvw  = p; p += WSZ;
    bf16* cow  = p; p += WSZ;
    bf16* cqb  = p; p += EMBED;
    bf16* cvb  = p; p += EMBED;
    bf16* cob  = p; p += EMBED;
    bf16* wq   = p; p += SZ;      // Q (post-RoPE), then attention output (in place)
    bf16* wk   = p; p += SZ;
    bf16* wvt  = p; p += SZ;      // V^T per head

    CvtArgs ca;
    const void* srcs[10] = {d_in[0], d_in[1], d_in[2], d_in[3], d_in[5],
                            d_in[6], d_in[8], d_in[4], d_in[7], d_in[9]};
    bf16* dsts[10] = {ch, ccos, csin, cqw, ckw, cvw, cow, cqb, cvb, cob};
    int   ns[10]   = {(int)SZ, (int)CS, (int)CS, (int)WSZ, (int)WSZ,
                      (int)WSZ, (int)WSZ, EMBED, EMBED, EMBED};
    int cum = 0;
    for (int i = 0; i < 10; ++i) {
        ca.src[i] = srcs[i]; ca.dst[i] = dsts[i]; ca.n[i] = ns[i];
        ca.cum[i] = cum;
        cum += (ns[i] + 2047) / 2048;
    }
    to_bf16_fused<<<cum, 256, 0, stream>>>(ca, disc);

    gemm_qkv<<<39 * 12, 512, 0, stream>>>(ch, cqw, ckw, cvw, cqb, cvb,
                                          ccos, csin, wq, wk, wvt, T_TOTAL);
    attn_kernel<<<dim3(153, 16), 256, 0, stream>>>(wq, wk, wvt, wq);
    gemm_out<<<39 * 4, 512, 0, stream>>>(wq, cow, cob, d_out, T_TOTAL, disc);
}